// Round 8
// baseline (264.644 us; speedup 1.0000x reference)
//
#include <hip/hip_runtime.h>
#include <hip/hip_bf16.h>

#define BB   131072
#define CC   16
#define DIN  256
#define DH   1024
#define DOUT 256
#define TM   128   // tokens per tile
#define NHB  16    // hidden blocks of 64
#define NB   512   // bucketing blocks (BB/NB = 256 tokens each)

typedef __attribute__((ext_vector_type(8))) short bf16x8;
typedef __attribute__((ext_vector_type(4))) short short4v;
typedef __attribute__((ext_vector_type(4))) float f32x4;

__device__ inline unsigned short f2b(float f) {
  union { float f; unsigned u; } v; v.f = f;
  unsigned u = v.u;
  return (unsigned short)((u + 0x7fffu + ((u >> 16) & 1u)) >> 16);  // RNE
}

__device__ inline void gload_lds16(const void* g, void* l) {
  __builtin_amdgcn_global_load_lds(
      (const __attribute__((address_space(1))) void*)g,
      (__attribute__((address_space(3))) void*)l, 16, 0, 0);
}

#define MFMA16(a, b, c) __builtin_amdgcn_mfma_f32_16x16x32_bf16((a), (b), (c), 0, 0, 0)

// ---------------- bucketing (contention-free counting sort) ----------------
__global__ void hist_k(const int* __restrict__ cat, int* __restrict__ blockhist) {
  __shared__ int h[CC];
  const int tid = threadIdx.x;
  if (tid < CC) h[tid] = 0;
  __syncthreads();
  const int i = blockIdx.x * 256 + tid;
  atomicAdd(&h[cat[i]], 1);
  __syncthreads();
  if (tid < CC) blockhist[blockIdx.x * CC + tid] = h[tid];
}

__global__ void offsets2_k(const int* __restrict__ blockhist,
                           int* __restrict__ counts, int* __restrict__ padoff,
                           int* __restrict__ base) {
  __shared__ int part[CC][64];
  __shared__ int pref[CC][64];
  __shared__ int scnt[CC];
  __shared__ int spad[CC + 1];
  const int tid = threadIdx.x;       // 1024 threads
  const int c = tid >> 6;
  const int g = tid & 63;
  int h[8];
  int s = 0;
#pragma unroll
  for (int i = 0; i < 8; i++) {
    h[i] = blockhist[(g * 8 + i) * CC + c];
    s += h[i];
  }
  part[c][g] = s;
  __syncthreads();
  if (g == 0) {
    int r = 0;
    for (int j = 0; j < 64; j++) { pref[c][j] = r; r += part[c][j]; }
    scnt[c] = r;
  }
  __syncthreads();
  if (tid == 0) {
    int acc = 0;
    for (int c2 = 0; c2 < CC; c2++) {
      spad[c2] = acc;
      padoff[c2] = acc;
      counts[c2] = scnt[c2];
      acc += ((scnt[c2] + TM - 1) / TM) * TM;
    }
    spad[CC] = acc;
    padoff[CC] = acc;
  }
  __syncthreads();
  int run = spad[c] + pref[c][g];
#pragma unroll
  for (int i = 0; i < 8; i++) {
    base[(g * 8 + i) * CC + c] = run;
    run += h[i];
  }
}

__global__ void scatter2_k(const int* __restrict__ cat, const int* __restrict__ base,
                           int* __restrict__ idx) {
  __shared__ int cur[CC];
  const int tid = threadIdx.x;
  if (tid < CC) cur[tid] = base[blockIdx.x * CC + tid];
  __syncthreads();
  const int i = blockIdx.x * 256 + tid;
  const int c = cat[i];
  const int pos = atomicAdd(&cur[c], 1);
  idx[pos] = i;
}

// -------- weight conversion: f32 -> bf16 in MFMA A-fragment order --------
// A-frag map (verified r1-r7): 16(row)x32(k) tile, lane = (row&15)+16*((k&31)>>3),
// byte j = (k&7)*2. Tiles stored [tile][lane][16B] = 1024 B.
// W1: per category [hb=16][nt=4][ks=8][lane][16B]  (32 KB per hb of 64 n)
__global__ void conv_w1_k(const float* __restrict__ W1, short* __restrict__ w1b) {
  int t = blockIdx.x * blockDim.x + threadIdx.x;   // 524288
  int n  = t & 1023;
  int j8 = (t >> 10) & 31;   // k-chunk of 8
  int c  = t >> 15;
  const float* src = W1 + (size_t)c * DIN * DH;
  bf16x8 o;
#pragma unroll
  for (int i = 0; i < 8; i++)
    o[i] = (short)f2b(src[(size_t)(j8 * 8 + i) * DH + n]);
  char* dst = (char*)w1b + (size_t)c * 524288
            + (n >> 6) * 32768 + ((n >> 4) & 3) * 8192 + (j8 >> 2) * 1024
            + ((n & 15) + 16 * (j8 & 3)) * 16;
  *(bf16x8*)dst = o;
}

// W2: per category [hb=16][nt=16][ks=2][lane][16B]  (32 KB per hb of 64 k)
__global__ void conv_w2_k(const float* __restrict__ W2, short* __restrict__ w2b) {
  int t = blockIdx.x * blockDim.x + threadIdx.x;   // 524288
  int n  = t & 255;
  int j8 = (t >> 8) & 127;   // k-chunk of 8 (k = hidden)
  int c  = t >> 15;
  const float* src = W2 + (size_t)c * DH * DOUT;
  bf16x8 o;
#pragma unroll
  for (int i = 0; i < 8; i++)
    o[i] = (short)f2b(src[(size_t)(j8 * 8 + i) * DOUT + n]);
  char* dst = (char*)w2b + (size_t)c * 524288
            + (j8 >> 3) * 32768 + (n >> 4) * 2048 + ((j8 >> 2) & 1) * 1024
            + ((n & 15) + 16 * (j8 & 3)) * 16;
  *(bf16x8*)dst = o;
}

// ---------------- fused routed MLP ----------------
// 512 thr, 8 waves = wt(4 token-tile PAIRS) x wh(2). Tile = 128 tokens.
// 16 hidden blocks of 64. 4-phase m201-style schedule per hb:
// each phase {ds_read issues | stage issue; BAR; lgkm(0); prio1; 16 MFMA; prio0; BAR}
// counted vmcnt(8)/(4) once per 2 phases, never 0 mid-loop.
// LDS: w1 dbuf 2x32K @0 | w2 dbuf 2x32K @64K | hs 16K @128K | toks | b1s | b2s
#define W2OFF  65536
#define HSOFF  131072
#define TKOFF  147456
#define B1OFF  147968
#define B2OFF  152064
#define SMSZ   153088

__launch_bounds__(512, 2)
__global__ void mlp_k(const float* __restrict__ x,
                      const float* __restrict__ b1,
                      const float* __restrict__ b2,
                      const short* __restrict__ w1b,
                      const short* __restrict__ w2b,
                      const int* __restrict__ idx,
                      const int* __restrict__ padoff,
                      const int* __restrict__ counts,
                      float* __restrict__ out) {
  __shared__ __align__(16) char sm[SMSZ];

  const int bhw = blockIdx.x;
  const int wg = (bhw & 7) * 130 + (bhw >> 3);   // XCD-chunked swizzle, 1040 = 8*130
  const int p = wg * TM;
  const int total = padoff[CC];
  if (p >= total) return;
  int c = 0;
  while (padoff[c + 1] <= p) c++;
  const int cnt = counts[c];
  const int start = p - padoff[c];

  const int tid  = threadIdx.x;
  const int lane = tid & 63;
  const int w    = tid >> 6;   // 0..7
  const int wt   = w >> 1;     // 0..3: token-tile pair {2wt, 2wt+1}
  const int wh   = w & 1;      // L1: n-tile pair {2wh,2wh+1} of 4; L2: out-half
  const int lrow = lane & 15;
  const int lgrp = lane >> 4;

  char*  hsb   = sm + HSOFF;
  int*   toksp = (int*)(sm + TKOFF);
  float* b1s   = (float*)(sm + B1OFF);
  float* b2s   = (float*)(sm + B2OFF);

  // ---- prologue: gather x, f32->bf16, B-frag order [tt=8][ks=8][lane][16B] ----
  {
    const int r = tid >> 2;      // 0..127 token slot
    const int q = tid & 3;       // 64-float chunk
    const int pos = start + r;
    int tok = (pos < cnt) ? idx[p + r] : -1;
    if (q == 0) toksp[r] = tok;
    char* tb = sm + (r >> 4) * 8192 + (r & 15) * 16;
    if (tok >= 0) {
      const f32x4* src = (const f32x4*)(x + (size_t)tok * DIN) + q * 16;
#pragma unroll
      for (int t = 0; t < 8; t++) {
        f32x4 v0 = src[2 * t];
        f32x4 v1 = src[2 * t + 1];
        bf16x8 o;
        o[0] = (short)f2b(v0[0]); o[1] = (short)f2b(v0[1]);
        o[2] = (short)f2b(v0[2]); o[3] = (short)f2b(v0[3]);
        o[4] = (short)f2b(v1[0]); o[5] = (short)f2b(v1[1]);
        o[6] = (short)f2b(v1[2]); o[7] = (short)f2b(v1[3]);
        *(bf16x8*)(tb + (2 * q + (t >> 2)) * 1024 + (t & 3) * 256) = o;
      }
    } else {
      bf16x8 z = {0, 0, 0, 0, 0, 0, 0, 0};
#pragma unroll
      for (int t = 0; t < 8; t++)
        *(bf16x8*)(tb + (2 * q + (t >> 2)) * 1024 + (t & 3) * 256) = z;
    }
    if (tid < 256) ((f32x4*)b1s)[tid] = ((const f32x4*)(b1 + (size_t)c * DH))[tid];
    if (tid < 64)  ((f32x4*)b2s)[tid] = ((const f32x4*)(b2 + (size_t)c * DOUT))[tid];
  }
  __syncthreads();

  // ---- x fragments to registers: 2 token tiles ----
  bf16x8 xf[2][8];
#pragma unroll
  for (int ti = 0; ti < 2; ti++)
#pragma unroll
    for (int ks = 0; ks < 8; ks++)
      xf[ti][ks] = *(const bf16x8*)(sm + (2 * wt + ti) * 8192 + ks * 1024 + lane * 16);
  __syncthreads();   // xs region free -> w1 double buffer

  const char* w1g = (const char*)w1b + (size_t)c * 524288;
  const char* w2g = (const char*)w2b + (size_t)c * 524288;

  auto stage1 = [&](int i) {   // 32 KB linear, 4 vm ops/thread
    const char* src = w1g + (size_t)i * 32768;
    char* dst = sm + (i & 1) * 32768;
#pragma unroll
    for (int j = 0; j < 4; j++) {
      int chunk = (w * 4 + j) * 1024;
      gload_lds16(src + chunk + lane * 16, dst + chunk);
    }
  };
  auto stage2 = [&](int i) {   // 32 KB linear, 4 vm ops/thread
    const char* src = w2g + (size_t)i * 32768;
    char* dst = sm + W2OFF + (i & 1) * 32768;
#pragma unroll
    for (int j = 0; j < 4; j++) {
      int chunk = (w * 4 + j) * 1024;
      gload_lds16(src + chunk + lane * 16, dst + chunk);
    }
  };

  stage1(0);
  stage2(0);
  asm volatile("s_waitcnt vmcnt(0)" ::: "memory");
  __syncthreads();

  f32x4 acc2[2][8];   // [token tile][out tile]
#pragma unroll
  for (int ti = 0; ti < 2; ti++)
#pragma unroll
    for (int ni = 0; ni < 8; ni++)
      acc2[ti][ni] = (f32x4){0.f, 0.f, 0.f, 0.f};

  for (int hb = 0; hb < NHB; hb++) {
    const char* w1c = sm + (hb & 1) * 32768;
    const char* w2c = sm + W2OFF + (hb & 1) * 32768;
    const bool notlast = (hb < NHB - 1);

    f32x4 acc1[2][2];   // [ti][nj]
#pragma unroll
    for (int ti = 0; ti < 2; ti++)
#pragma unroll
      for (int nj = 0; nj < 2; nj++)
        acc1[ti][nj] = (f32x4){0.f, 0.f, 0.f, 0.f};

    // ===== P1: read w1 nt(2wh) | issue stage1(hb+1) | 16 MFMA =====
    {
      bf16x8 a[8];
#pragma unroll
      for (int ks = 0; ks < 8; ks++)
        a[ks] = *(const bf16x8*)(w1c + (2 * wh) * 8192 + ks * 1024 + lane * 16);
      if (notlast) stage1(hb + 1);
      __builtin_amdgcn_s_barrier();
      asm volatile("s_waitcnt lgkmcnt(0)" ::: "memory");
      __builtin_amdgcn_sched_barrier(0);
      __builtin_amdgcn_s_setprio(1);
#pragma unroll
      for (int ks = 0; ks < 8; ks++) {
        acc1[0][0] = MFMA16(a[ks], xf[0][ks], acc1[0][0]);
        acc1[1][0] = MFMA16(a[ks], xf[1][ks], acc1[1][0]);
      }
      __builtin_amdgcn_s_setprio(0);
      __builtin_amdgcn_s_barrier();
    }

    // ===== P2: read w1 nt(2wh+1) | issue stage2(hb+1) | 16 MFMA | pack hs =====
    {
      bf16x8 a[8];
#pragma unroll
      for (int ks = 0; ks < 8; ks++)
        a[ks] = *(const bf16x8*)(w1c + (2 * wh + 1) * 8192 + ks * 1024 + lane * 16);
      if (notlast) stage2(hb + 1);
      __builtin_amdgcn_s_barrier();
      asm volatile("s_waitcnt lgkmcnt(0)" ::: "memory");
      __builtin_amdgcn_sched_barrier(0);
      __builtin_amdgcn_s_setprio(1);
#pragma unroll
      for (int ks = 0; ks < 8; ks++) {
        acc1[0][1] = MFMA16(a[ks], xf[0][ks], acc1[0][1]);
        acc1[1][1] = MFMA16(a[ks], xf[1][ks], acc1[1][1]);
      }
      __builtin_amdgcn_s_setprio(0);
      // bias+relu, pack into hs B-frag order: [tt=8][ks=2][lane][16B]
#pragma unroll
      for (int nj = 0; nj < 2; nj++) {
        f32x4 bv = *(const f32x4*)(b1s + hb * 64 + (2 * wh + nj) * 16 + lgrp * 4);
#pragma unroll
        for (int ti = 0; ti < 2; ti++) {
          short4v h;
#pragma unroll
          for (int jj = 0; jj < 4; jj++)
            h[jj] = (short)f2b(fmaxf(acc1[ti][nj][jj] + bv[jj], 0.0f));
          *(short4v*)(hsb + (2 * wt + ti) * 2048 + wh * 1024
                      + (lrow + 16 * (2 * nj + (lgrp >> 1))) * 16 + (lgrp & 1) * 8) = h;
        }
      }
      // w2[hb] landed (8 newest = stage1/2(hb+1) may fly); hs visible after barrier
      if (notlast)
        asm volatile("s_waitcnt vmcnt(8) lgkmcnt(0)" ::: "memory");
      else
        asm volatile("s_waitcnt vmcnt(0) lgkmcnt(0)" ::: "memory");
      __builtin_amdgcn_s_barrier();
    }

    // ===== P3: read hs(ks0) + w2(ks0) | 16 MFMA =====
    {
      bf16x8 hf0 = *(const bf16x8*)(hsb + (2 * wt + 0) * 2048 + lane * 16);
      bf16x8 hf1 = *(const bf16x8*)(hsb + (2 * wt + 1) * 2048 + lane * 16);
      bf16x8 a2[8];
#pragma unroll
      for (int ni = 0; ni < 8; ni++)
        a2[ni] = *(const bf16x8*)(w2c + (wh * 8 + ni) * 2048 + lane * 16);
      __builtin_amdgcn_s_barrier();
      asm volatile("s_waitcnt lgkmcnt(0)" ::: "memory");
      __builtin_amdgcn_sched_barrier(0);
      __builtin_amdgcn_s_setprio(1);
#pragma unroll
      for (int ni = 0; ni < 8; ni++) {
        acc2[0][ni] = MFMA16(a2[ni], hf0, acc2[0][ni]);
        acc2[1][ni] = MFMA16(a2[ni], hf1, acc2[1][ni]);
      }
      __builtin_amdgcn_s_setprio(0);
      __builtin_amdgcn_s_barrier();
    }

    // ===== P4: read hs(ks1) + w2(ks1) | 16 MFMA | vmcnt(4) =====
    {
      bf16x8 hf0 = *(const bf16x8*)(hsb + (2 * wt + 0) * 2048 + 1024 + lane * 16);
      bf16x8 hf1 = *(const bf16x8*)(hsb + (2 * wt + 1) * 2048 + 1024 + lane * 16);
      bf16x8 a2[8];
#pragma unroll
      for (int ni = 0; ni < 8; ni++)
        a2[ni] = *(const bf16x8*)(w2c + (wh * 8 + ni) * 2048 + 1024 + lane * 16);
      __builtin_amdgcn_s_barrier();
      asm volatile("s_waitcnt lgkmcnt(0)" ::: "memory");
      __builtin_amdgcn_sched_barrier(0);
      __builtin_amdgcn_s_setprio(1);
#pragma unroll
      for (int ni = 0; ni < 8; ni++) {
        acc2[0][ni] = MFMA16(a2[ni], hf0, acc2[0][ni]);
        acc2[1][ni] = MFMA16(a2[ni], hf1, acc2[1][ni]);
      }
      __builtin_amdgcn_s_setprio(0);
      // w1[hb+1] landed (4 newest = stage2(hb+1) may fly)
      if (notlast)
        asm volatile("s_waitcnt vmcnt(4)" ::: "memory");
      __builtin_amdgcn_s_barrier();
    }
  }

  // ---- epilogue: + b2, vectorized scatter ----
#pragma unroll
  for (int ti = 0; ti < 2; ti++) {
    const int tok = toksp[(2 * wt + ti) * 16 + lrow];
    if (tok >= 0) {
#pragma unroll
      for (int ni = 0; ni < 8; ni++) {
        const int n0 = (wh * 8 + ni) * 16 + lgrp * 4;
        f32x4 bv = *(const f32x4*)(b2s + n0);
        f32x4 v = acc2[ti][ni] + bv;
        *(f32x4*)(out + (size_t)tok * DOUT + n0) = v;
      }
    }
  }
}

extern "C" void kernel_launch(void* const* d_in, const int* in_sizes, int n_in,
                              void* d_out, int out_size, void* d_ws, size_t ws_size,
                              hipStream_t stream) {
  (void)in_sizes; (void)n_in; (void)out_size; (void)ws_size;
  const float* x   = (const float*)d_in[0];
  const int*   cat = (const int*)d_in[1];
  const float* W1  = (const float*)d_in[2];
  const float* b1  = (const float*)d_in[3];
  const float* W2  = (const float*)d_in[4];
  const float* b2  = (const float*)d_in[5];
  float* out = (float*)d_out;

  char* ws = (char*)d_ws;
  int* counts    = (int*)(ws);
  int* padoff    = (int*)(ws + 128);
  int* blockhist = (int*)(ws + 4096);
  int* base      = (int*)(ws + 65536);
  int* idx       = (int*)(ws + 131072);
  short* w1b     = (short*)(ws + (1 << 20));
  short* w2b     = (short*)(ws + (1 << 20) + 8388608);

  hist_k<<<NB, 256, 0, stream>>>(cat, blockhist);
  offsets2_k<<<1, 1024, 0, stream>>>(blockhist, counts, padoff, base);
  scatter2_k<<<NB, 256, 0, stream>>>(cat, base, idx);
  conv_w1_k<<<2048, 256, 0, stream>>>(W1, w1b);
  conv_w2_k<<<2048, 256, 0, stream>>>(W2, w2b);

  const int ntiles = BB / TM + CC;   // 1040 = 8 * 130 (swizzle assumes this)
  mlp_k<<<ntiles, 512, 0, stream>>>(x, b1, b2, w1b, w2b, idx, padoff, counts, out);
}

// Round 9
// 243.717 us; speedup vs baseline: 1.0859x; 1.0859x over previous
//
#include <hip/hip_runtime.h>
#include <hip/hip_bf16.h>

#define BB   131072
#define CC   16
#define DIN  256
#define DH   1024
#define DOUT 256
#define TM   128   // tokens per tile
#define NHB  32    // hidden blocks of 32
#define NB   512   // bucketing blocks (BB/NB = 256 tokens each)

typedef __attribute__((ext_vector_type(8))) short bf16x8;
typedef __attribute__((ext_vector_type(4))) short short4v;
typedef __attribute__((ext_vector_type(4))) float f32x4;

__device__ inline unsigned short f2b(float f) {
  union { float f; unsigned u; } v; v.f = f;
  unsigned u = v.u;
  return (unsigned short)((u + 0x7fffu + ((u >> 16) & 1u)) >> 16);  // RNE
}

__device__ inline void gload_lds16(const void* g, void* l) {
  __builtin_amdgcn_global_load_lds(
      (const __attribute__((address_space(1))) void*)g,
      (__attribute__((address_space(3))) void*)l, 16, 0, 0);
}

#define MFMA16(a, b, c) __builtin_amdgcn_mfma_f32_16x16x32_bf16((a), (b), (c), 0, 0, 0)

// ---------------- bucketing (contention-free counting sort) ----------------
__global__ void hist_k(const int* __restrict__ cat, int* __restrict__ blockhist) {
  __shared__ int h[CC];
  const int tid = threadIdx.x;
  if (tid < CC) h[tid] = 0;
  __syncthreads();
  const int i = blockIdx.x * 256 + tid;
  atomicAdd(&h[cat[i]], 1);
  __syncthreads();
  if (tid < CC) blockhist[blockIdx.x * CC + tid] = h[tid];
}

__global__ void offsets2_k(const int* __restrict__ blockhist,
                           int* __restrict__ counts, int* __restrict__ padoff,
                           int* __restrict__ base) {
  __shared__ int part[CC][64];
  __shared__ int pref[CC][64];
  __shared__ int scnt[CC];
  __shared__ int spad[CC + 1];
  const int tid = threadIdx.x;       // 1024 threads
  const int c = tid >> 6;
  const int g = tid & 63;
  int h[8];
  int s = 0;
#pragma unroll
  for (int i = 0; i < 8; i++) {
    h[i] = blockhist[(g * 8 + i) * CC + c];
    s += h[i];
  }
  part[c][g] = s;
  __syncthreads();
  if (g == 0) {
    int r = 0;
    for (int j = 0; j < 64; j++) { pref[c][j] = r; r += part[c][j]; }
    scnt[c] = r;
  }
  __syncthreads();
  if (tid == 0) {
    int acc = 0;
    for (int c2 = 0; c2 < CC; c2++) {
      spad[c2] = acc;
      padoff[c2] = acc;
      counts[c2] = scnt[c2];
      acc += ((scnt[c2] + TM - 1) / TM) * TM;
    }
    spad[CC] = acc;
    padoff[CC] = acc;
  }
  __syncthreads();
  int run = spad[c] + pref[c][g];
#pragma unroll
  for (int i = 0; i < 8; i++) {
    base[(g * 8 + i) * CC + c] = run;
    run += h[i];
  }
}

__global__ void scatter2_k(const int* __restrict__ cat, const int* __restrict__ base,
                           int* __restrict__ idx) {
  __shared__ int cur[CC];
  const int tid = threadIdx.x;
  if (tid < CC) cur[tid] = base[blockIdx.x * CC + tid];
  __syncthreads();
  const int i = blockIdx.x * 256 + tid;
  const int c = cat[i];
  const int pos = atomicAdd(&cur[c], 1);
  idx[pos] = i;
}

// -------- weight conversion: f32 -> bf16 in MFMA A-fragment order --------
// A-frag map (verified r1-r8): 16(row)x32(k) tile, lane = (row&15)+16*((k&31)>>3),
// byte j = (k&7)*2. Tiles stored [tile][lane][16B] = 1024 B.
// W1: per category [hb=32][nt=2][ks=8][lane][16B]  (16 KB per hb of 32 n)
__global__ void conv_w1_k(const float* __restrict__ W1, short* __restrict__ w1b) {
  int t = blockIdx.x * blockDim.x + threadIdx.x;   // 524288
  int n  = t & 1023;
  int j8 = (t >> 10) & 31;   // k-chunk of 8
  int c  = t >> 15;
  const float* src = W1 + (size_t)c * DIN * DH;
  bf16x8 o;
#pragma unroll
  for (int i = 0; i < 8; i++)
    o[i] = (short)f2b(src[(size_t)(j8 * 8 + i) * DH + n]);
  char* dst = (char*)w1b + (size_t)c * 524288
            + (n >> 5) * 16384 + ((n >> 4) & 1) * 8192 + (j8 >> 2) * 1024
            + ((n & 15) + 16 * (j8 & 3)) * 16;
  *(bf16x8*)dst = o;
}

// W2: per category [kb=32][nt=16][lane][16B]  (16 KB per k-block of 32)
__global__ void conv_w2_k(const float* __restrict__ W2, short* __restrict__ w2b) {
  int t = blockIdx.x * blockDim.x + threadIdx.x;   // 524288
  int n  = t & 255;
  int j8 = (t >> 8) & 127;   // k-chunk of 8 (k = hidden)
  int c  = t >> 15;
  const float* src = W2 + (size_t)c * DH * DOUT;
  bf16x8 o;
#pragma unroll
  for (int i = 0; i < 8; i++)
    o[i] = (short)f2b(src[(size_t)(j8 * 8 + i) * DOUT + n]);
  char* dst = (char*)w2b + (size_t)c * 524288
            + (j8 >> 2) * 16384 + (n >> 4) * 1024
            + ((n & 15) + 16 * (j8 & 3)) * 16;
  *(bf16x8*)dst = o;
}

// ---------------- fused routed MLP ----------------
// 512 thr, 8 waves = wt(4 token-tile PAIRS of 16) x wh(2). Tile = 128 tokens.
// 32 hidden blocks of 32. Merged regions: R(i) = L2(i-1) + L1(i), ONE barrier
// per region, stage issued at region start + single vmcnt(0)+lgkm(0) drain at
// region end (full-region latency cover -> drain is free in steady state).
// LDS: w1 dbuf 2x16K @0 | w2 dbuf 2x16K @32K | hs dbuf 2x8K @64K | toks | b1s | b2s
#define W2OFF  32768
#define HSOFF  65536
#define TKOFF  81920
#define B1OFF  82432
#define B2OFF  86528
#define SMSZ   87552

__launch_bounds__(512, 2)
__global__ void mlp_k(const float* __restrict__ x,
                      const float* __restrict__ b1,
                      const float* __restrict__ b2,
                      const short* __restrict__ w1b,
                      const short* __restrict__ w2b,
                      const int* __restrict__ idx,
                      const int* __restrict__ padoff,
                      const int* __restrict__ counts,
                      float* __restrict__ out) {
  __shared__ __align__(16) char sm[SMSZ];

  const int bhw = blockIdx.x;
  const int wg = (bhw & 7) * 130 + (bhw >> 3);   // XCD-chunked swizzle, 1040 = 8*130
  const int p = wg * TM;
  const int total = padoff[CC];
  if (p >= total) return;
  int c = 0;
  while (padoff[c + 1] <= p) c++;
  const int cnt = counts[c];
  const int start = p - padoff[c];

  const int tid  = threadIdx.x;
  const int lane = tid & 63;
  const int w    = tid >> 6;   // 0..7
  const int wt   = w >> 1;     // 0..3: token-tile pair {2wt, 2wt+1}
  const int wh   = w & 1;      // L1: n-tile (1 of 2); L2: out-half (8 of 16 nt)
  const int lrow = lane & 15;
  const int lgrp = lane >> 4;

  char*  hsb   = sm + HSOFF;
  int*   toksp = (int*)(sm + TKOFF);
  float* b1s   = (float*)(sm + B1OFF);
  float* b2s   = (float*)(sm + B2OFF);

  // ---- prologue: gather x, f32->bf16, B-frag order [tt=8][ks=8][lane][16B] ----
  {
    const int r = tid >> 2;      // 0..127 token slot
    const int q = tid & 3;       // 64-float chunk
    const int pos = start + r;
    int tok = (pos < cnt) ? idx[p + r] : -1;
    if (q == 0) toksp[r] = tok;
    char* tb = sm + (r >> 4) * 8192 + (r & 15) * 16;
    if (tok >= 0) {
      const f32x4* src = (const f32x4*)(x + (size_t)tok * DIN) + q * 16;
#pragma unroll
      for (int t = 0; t < 8; t++) {
        f32x4 v0 = src[2 * t];
        f32x4 v1 = src[2 * t + 1];
        bf16x8 o;
        o[0] = (short)f2b(v0[0]); o[1] = (short)f2b(v0[1]);
        o[2] = (short)f2b(v0[2]); o[3] = (short)f2b(v0[3]);
        o[4] = (short)f2b(v1[0]); o[5] = (short)f2b(v1[1]);
        o[6] = (short)f2b(v1[2]); o[7] = (short)f2b(v1[3]);
        *(bf16x8*)(tb + (2 * q + (t >> 2)) * 1024 + (t & 3) * 256) = o;
      }
    } else {
      bf16x8 z = {0, 0, 0, 0, 0, 0, 0, 0};
#pragma unroll
      for (int t = 0; t < 8; t++)
        *(bf16x8*)(tb + (2 * q + (t >> 2)) * 1024 + (t & 3) * 256) = z;
    }
    if (tid < 256) ((f32x4*)b1s)[tid] = ((const f32x4*)(b1 + (size_t)c * DH))[tid];
    if (tid < 64)  ((f32x4*)b2s)[tid] = ((const f32x4*)(b2 + (size_t)c * DOUT))[tid];
  }
  __syncthreads();

  // ---- x fragments to registers: 2 token tiles ----
  bf16x8 xf[2][8];
#pragma unroll
  for (int ti = 0; ti < 2; ti++)
#pragma unroll
    for (int ks = 0; ks < 8; ks++)
      xf[ti][ks] = *(const bf16x8*)(sm + (2 * wt + ti) * 8192 + ks * 1024 + lane * 16);
  __syncthreads();   // all xf reads done; xs region becomes weight buffers

  const char* w1g = (const char*)w1b + (size_t)c * 524288;
  const char* w2g = (const char*)w2b + (size_t)c * 524288;

  auto stage1 = [&](int i) {   // 16 KB linear, 2 vm ops/thread
    const char* src = w1g + (size_t)i * 16384;
    char* dst = sm + (i & 1) * 16384;
#pragma unroll
    for (int j = 0; j < 2; j++) {
      int chunk = (w * 2 + j) * 1024;
      gload_lds16(src + chunk + lane * 16, dst + chunk);
    }
  };
  auto stage2 = [&](int i) {   // 16 KB linear, 2 vm ops/thread
    const char* src = w2g + (size_t)i * 16384;
    char* dst = sm + W2OFF + (i & 1) * 16384;
#pragma unroll
    for (int j = 0; j < 2; j++) {
      int chunk = (w * 2 + j) * 1024;
      gload_lds16(src + chunk + lane * 16, dst + chunk);
    }
  };

  f32x4 acc2[2][8];   // [token tile][out tile]
#pragma unroll
  for (int ti = 0; ti < 2; ti++)
#pragma unroll
    for (int ni = 0; ni < 8; ni++)
      acc2[ti][ni] = (f32x4){0.f, 0.f, 0.f, 0.f};

  const int hswr = (lrow + 16 * (wh * 2 + (lgrp >> 1))) * 16 + (lgrp & 1) * 8;

  // prologue staging: w1[0] published for R(0)
  stage1(0);
  asm volatile("s_waitcnt vmcnt(0)" ::: "memory");
  __builtin_amdgcn_s_barrier();

  // ===== R(0): issue stage2(0)+stage1(1); L1(0) -> hs[0] =====
  {
    stage2(0);
    stage1(1);
    const char* w1c = sm + wh * 8192;     // buf 0
    f32x4 p0 = (f32x4){0.f, 0.f, 0.f, 0.f};
    f32x4 p1 = (f32x4){0.f, 0.f, 0.f, 0.f};
    __builtin_amdgcn_s_setprio(1);
#pragma unroll
    for (int ks = 0; ks < 8; ks++) {
      bf16x8 a = *(const bf16x8*)(w1c + ks * 1024 + lane * 16);
      p0 = MFMA16(a, xf[0][ks], p0);
      p1 = MFMA16(a, xf[1][ks], p1);
    }
    __builtin_amdgcn_s_setprio(0);
    f32x4 bv = *(const f32x4*)(b1s + wh * 16 + lgrp * 4);
    short4v h0, h1;
#pragma unroll
    for (int jj = 0; jj < 4; jj++) {
      h0[jj] = (short)f2b(fmaxf(p0[jj] + bv[jj], 0.0f));
      h1[jj] = (short)f2b(fmaxf(p1[jj] + bv[jj], 0.0f));
    }
    *(short4v*)(hsb + (2 * wt) * 1024 + hswr)     = h0;
    *(short4v*)(hsb + (2 * wt + 1) * 1024 + hswr) = h1;
    asm volatile("s_waitcnt vmcnt(0) lgkmcnt(0)" ::: "memory");
    __builtin_amdgcn_s_barrier();
  }

  // ===== R(i) = L2(i-1) + L1(i), i = 1..31 =====
  for (int i = 1; i < NHB; i++) {
    stage2(i);
    if (i < NHB - 1) stage1(i + 1);

    const char* hr  = hsb + ((i - 1) & 1) * 8192;
    const char* w2c = sm + W2OFF + ((i - 1) & 1) * 16384;
    const char* w1c = sm + (i & 1) * 16384 + wh * 8192;

    bf16x8 hf0 = *(const bf16x8*)(hr + (2 * wt) * 1024 + lane * 16);
    bf16x8 hf1 = *(const bf16x8*)(hr + (2 * wt + 1) * 1024 + lane * 16);

    __builtin_amdgcn_s_setprio(1);
#pragma unroll
    for (int ni = 0; ni < 8; ni++) {
      bf16x8 a2 = *(const bf16x8*)(w2c + (wh * 8 + ni) * 1024 + lane * 16);
      acc2[0][ni] = MFMA16(a2, hf0, acc2[0][ni]);
      acc2[1][ni] = MFMA16(a2, hf1, acc2[1][ni]);
    }
    f32x4 p0 = (f32x4){0.f, 0.f, 0.f, 0.f};
    f32x4 p1 = (f32x4){0.f, 0.f, 0.f, 0.f};
#pragma unroll
    for (int ks = 0; ks < 8; ks++) {
      bf16x8 a = *(const bf16x8*)(w1c + ks * 1024 + lane * 16);
      p0 = MFMA16(a, xf[0][ks], p0);
      p1 = MFMA16(a, xf[1][ks], p1);
    }
    __builtin_amdgcn_s_setprio(0);

    f32x4 bv = *(const f32x4*)(b1s + i * 32 + wh * 16 + lgrp * 4);
    short4v h0, h1;
#pragma unroll
    for (int jj = 0; jj < 4; jj++) {
      h0[jj] = (short)f2b(fmaxf(p0[jj] + bv[jj], 0.0f));
      h1[jj] = (short)f2b(fmaxf(p1[jj] + bv[jj], 0.0f));
    }
    char* hw = hsb + (i & 1) * 8192;
    *(short4v*)(hw + (2 * wt) * 1024 + hswr)     = h0;
    *(short4v*)(hw + (2 * wt + 1) * 1024 + hswr) = h1;

    // single drain per region: staged loads got a full region of cover
    asm volatile("s_waitcnt vmcnt(0) lgkmcnt(0)" ::: "memory");
    __builtin_amdgcn_s_barrier();
  }

  // ===== tail: L2(31) =====
  {
    const char* hr  = hsb + ((NHB - 1) & 1) * 8192;
    const char* w2c = sm + W2OFF + ((NHB - 1) & 1) * 16384;
    bf16x8 hf0 = *(const bf16x8*)(hr + (2 * wt) * 1024 + lane * 16);
    bf16x8 hf1 = *(const bf16x8*)(hr + (2 * wt + 1) * 1024 + lane * 16);
#pragma unroll
    for (int ni = 0; ni < 8; ni++) {
      bf16x8 a2 = *(const bf16x8*)(w2c + (wh * 8 + ni) * 1024 + lane * 16);
      acc2[0][ni] = MFMA16(a2, hf0, acc2[0][ni]);
      acc2[1][ni] = MFMA16(a2, hf1, acc2[1][ni]);
    }
  }

  // ---- epilogue: + b2, vectorized scatter ----
#pragma unroll
  for (int ti = 0; ti < 2; ti++) {
    const int tok = toksp[(2 * wt + ti) * 16 + lrow];
    if (tok >= 0) {
#pragma unroll
      for (int ni = 0; ni < 8; ni++) {
        const int n0 = (wh * 8 + ni) * 16 + lgrp * 4;
        f32x4 bv = *(const f32x4*)(b2s + n0);
        f32x4 v = acc2[ti][ni] + bv;
        *(f32x4*)(out + (size_t)tok * DOUT + n0) = v;
      }
    }
  }
}

extern "C" void kernel_launch(void* const* d_in, const int* in_sizes, int n_in,
                              void* d_out, int out_size, void* d_ws, size_t ws_size,
                              hipStream_t stream) {
  (void)in_sizes; (void)n_in; (void)out_size; (void)ws_size;
  const float* x   = (const float*)d_in[0];
  const int*   cat = (const int*)d_in[1];
  const float* W1  = (const float*)d_in[2];
  const float* b1  = (const float*)d_in[3];
  const float* W2  = (const float*)d_in[4];
  const float* b2  = (const float*)d_in[5];
  float* out = (float*)d_out;

  char* ws = (char*)d_ws;
  int* counts    = (int*)(ws);
  int* padoff    = (int*)(ws + 128);
  int* blockhist = (int*)(ws + 4096);
  int* base      = (int*)(ws + 65536);
  int* idx       = (int*)(ws + 131072);
  short* w1b     = (short*)(ws + (1 << 20));
  short* w2b     = (short*)(ws + (1 << 20) + 8388608);

  hist_k<<<NB, 256, 0, stream>>>(cat, blockhist);
  offsets2_k<<<1, 1024, 0, stream>>>(blockhist, counts, padoff, base);
  scatter2_k<<<NB, 256, 0, stream>>>(cat, base, idx);
  conv_w1_k<<<2048, 256, 0, stream>>>(W1, w1b);
  conv_w2_k<<<2048, 256, 0, stream>>>(W2, w2b);

  const int ntiles = BB / TM + CC;   // 1040 = 8 * 130 (swizzle assumes this)
  mlp_k<<<ntiles, 512, 0, stream>>>(x, b1, b2, w1b, w2b, idx, padoff, counts, out);
}